// Round 8
// baseline (1721.164 us; speedup 1.0000x reference)
//
#include <hip/hip_runtime.h>
#include <stdint.h>
#include <math.h>

#define NN 32768      // total nodes
#define EE 262144     // edges per edge set (before self loops)
#define DD 128
#define NPG 1024
#define NB 32
#define NEG_SLOPE 0.2f
#define USE_PARTITIONABLE 1

// ---------------- threefry2x32 (exact JAX algorithm) ----------------
__host__ __device__ inline void tf2x32(uint32_t k0, uint32_t k1, uint32_t c0, uint32_t c1,
                                       uint32_t* o0, uint32_t* o1) {
  uint32_t ks2 = k0 ^ k1 ^ 0x1BD11BDAu;
  uint32_t x0 = c0 + k0;
  uint32_t x1 = c1 + k1;
#define TFR(r) { x0 += x1; x1 = (x1 << (r)) | (x1 >> (32 - (r))); x1 ^= x0; }
  TFR(13) TFR(15) TFR(26) TFR(6)
  x0 += k1; x1 += ks2 + 1u;
  TFR(17) TFR(29) TFR(16) TFR(24)
  x0 += ks2; x1 += k0 + 2u;
  TFR(13) TFR(15) TFR(26) TFR(6)
  x0 += k0; x1 += k1 + 3u;
  TFR(17) TFR(29) TFR(16) TFR(24)
  x0 += k1; x1 += ks2 + 4u;
  TFR(13) TFR(15) TFR(26) TFR(6)
  x0 += ks2; x1 += k0 + 5u;
#undef TFR
  *o0 = x0; *o1 = x1;
}

__device__ inline float gumbel_from_bits(uint32_t bits) {
  float fl = __uint_as_float((bits >> 9) | 0x3f800000u) - 1.0f;
  const float tiny = 1.17549435e-38f;
  float u = fmaxf(tiny, fl + tiny);
  return -logf(-logf(u));
}

__device__ inline float gumbel_at(uint32_t ka, uint32_t kb, uint32_t f) {
#if USE_PARTITIONABLE
  uint32_t o0, o1;
  tf2x32(ka, kb, 0u, f, &o0, &o1);   // counter = 64-bit flat index (hi=0, lo=f)
  return gumbel_from_bits(o0 ^ o1);  // 32-bit draw = XOR fold of both words
#else
  const uint32_t HALF = 16368u;
  uint32_t o0, o1;
  if (f < HALF) { tf2x32(ka, kb, f, f + HALF, &o0, &o1); return gumbel_from_bits(o0); }
  else          { tf2x32(ka, kb, f - HALF, f, &o0, &o1); return gumbel_from_bits(o1); }
#endif
}

// ---------------- batched CSR build ----------------
__global__ __launch_bounds__(256) void hist3_kernel(const int* __restrict__ e0,
                                                    const int* __restrict__ e1,
                                                    const int* __restrict__ e2,
                                                    int* __restrict__ counts3) {
  int s = blockIdx.x >> 10;
  int i = (blockIdx.x & 1023) * 256 + threadIdx.x;
  const int* d = (s == 0) ? e0 : (s == 1) ? e1 : e2;
  atomicAdd(&counts3[s * NN + d[i + EE]], 1);
}

__global__ __launch_bounds__(1024) void scan3_kernel(const int* __restrict__ counts3,
                                                     int* __restrict__ rowptrAll,
                                                     int* __restrict__ cursorAll) {
  __shared__ int part[1024];
  int s = blockIdx.x;
  const int* counts = counts3 + s * NN;
  int* rowptr = rowptrAll + s * (NN + 1);
  int* cursor = cursorAll + s * NN;
  int t = threadIdx.x;
  int base = t * 32;
  int local[32];
  {
    const int4* c4 = (const int4*)(counts + base);
    int sum = 0;
#pragma unroll
    for (int v = 0; v < 8; v++) {
      int4 cc = c4[v];
      local[v * 4 + 0] = sum; sum += cc.x;
      local[v * 4 + 1] = sum; sum += cc.y;
      local[v * 4 + 2] = sum; sum += cc.z;
      local[v * 4 + 3] = sum; sum += cc.w;
    }
    part[t] = sum;
  }
  __syncthreads();
  int own = part[t];
  for (int off = 1; off < 1024; off <<= 1) {
    int v = (t >= off) ? part[t - off] : 0;
    __syncthreads();
    part[t] += v;
    __syncthreads();
  }
  int excl = part[t] - own;
  {
    int4* rp4 = (int4*)(rowptr + base);
    int4* cu4 = (int4*)(cursor + base);
#pragma unroll
    for (int v = 0; v < 8; v++) {
      int4 w;
      w.x = excl + local[v * 4 + 0];
      w.y = excl + local[v * 4 + 1];
      w.z = excl + local[v * 4 + 2];
      w.w = excl + local[v * 4 + 3];
      rp4[v] = w;
      cu4[v] = w;
    }
  }
  if (t == 1023) rowptr[NN] = part[1023];
}

__global__ __launch_bounds__(256) void scatter3_kernel(const int* __restrict__ e0,
                                                       const int* __restrict__ e1,
                                                       const int* __restrict__ e2,
                                                       int* __restrict__ cursorAll,
                                                       int* __restrict__ colAll) {
  int s = blockIdx.x >> 10;
  int i = (blockIdx.x & 1023) * 256 + threadIdx.x;
  const int* e = (s == 0) ? e0 : (s == 1) ? e1 : e2;
  int src = e[i], dst = e[i + EE];
  int p = atomicAdd(&cursorAll[s * NN + dst], 1);
  colAll[(size_t)s * EE + p] = src;
}

// ---------------- gemm8_kernel: out[128-row tile][128] = in@W (+bias) ----------------
// 256 threads, 8x8 thread tile (cols 4*tcg and 4*tcg+64), double-buffered k-chunks of 16.
// Pipeline per chunk: load-next(global) -> compute(cur) -> write-next -> ONE barrier.
#define FMA4(ac, s, v) { ac.x += (s) * (v).x; ac.y += (s) * (v).y; \
                         ac.z += (s) * (v).z; ac.w += (s) * (v).w; }

__global__ __launch_bounds__(256, 2) void gemm8_kernel(const float* __restrict__ in,
                                                       const float* __restrict__ W,
                                                       const float* __restrict__ bias,
                                                       float* __restrict__ out) {
  __shared__ __align__(16) float at[2][16 * 132];  // A^T chunk (pitch 132: 2-way max)
  __shared__ __align__(16) float ws[2][16 * 128];  // W chunk
  int t = threadIdx.x;
  size_t row0 = (size_t)blockIdx.x * 128;
  int tr = t >> 4, tcg = t & 15;   // 16 row-groups x 16 col-groups
  int r0 = tr * 8;
  float4 acc0[8], acc1[8];
#pragma unroll
  for (int i = 0; i < 8; i++) {
    acc0[i] = make_float4(0.f, 0.f, 0.f, 0.f);
    acc1[i] = make_float4(0.f, 0.f, 0.f, 0.f);
  }
  int srow = t >> 2;          // 0..63
  int sc4 = (t & 3) * 4;      // 0,4,8,12
  int kkA = t >> 5;           // 0..7  (W-stage row for first f4)
  int jgA = (t & 31) * 4;     // 0..124

  float4 a0, a1, w0, w1;
  auto load_chunk = [&](int k0) {
    a0 = *(const float4*)&in[(row0 + srow) * DD + k0 + sc4];
    a1 = *(const float4*)&in[(row0 + srow + 64) * DD + k0 + sc4];
    w0 = *(const float4*)&W[(size_t)(k0 + kkA) * DD + jgA];
    w1 = *(const float4*)&W[(size_t)(k0 + kkA + 8) * DD + jgA];
  };
  auto write_chunk = [&](int b) {
    float* A = at[b];
    A[(sc4 + 0) * 132 + srow] = a0.x;
    A[(sc4 + 1) * 132 + srow] = a0.y;
    A[(sc4 + 2) * 132 + srow] = a0.z;
    A[(sc4 + 3) * 132 + srow] = a0.w;
    A[(sc4 + 0) * 132 + srow + 64] = a1.x;
    A[(sc4 + 1) * 132 + srow + 64] = a1.y;
    A[(sc4 + 2) * 132 + srow + 64] = a1.z;
    A[(sc4 + 3) * 132 + srow + 64] = a1.w;
    float* Wd = ws[b];
    *(float4*)&Wd[kkA * 128 + jgA] = w0;
    *(float4*)&Wd[(kkA + 8) * 128 + jgA] = w1;
  };

  load_chunk(0);
  write_chunk(0);
  __syncthreads();
  for (int kc = 0; kc < 8; ++kc) {
    int cur = kc & 1;
    if (kc < 7) load_chunk((kc + 1) * 16);
    const float* A = at[cur];
    const float* Wd = ws[cur];
#pragma unroll
    for (int kk = 0; kk < 16; ++kk) {
      float4 av0 = *(const float4*)&A[kk * 132 + r0];
      float4 av1 = *(const float4*)&A[kk * 132 + r0 + 4];
      float4 wv0 = *(const float4*)&Wd[kk * 128 + 4 * tcg];
      float4 wv1 = *(const float4*)&Wd[kk * 128 + 4 * tcg + 64];
      float as[8] = {av0.x, av0.y, av0.z, av0.w, av1.x, av1.y, av1.z, av1.w};
#pragma unroll
      for (int i = 0; i < 8; i++) {
        FMA4(acc0[i], as[i], wv0);
        FMA4(acc1[i], as[i], wv1);
      }
    }
    if (kc < 7) {
      write_chunk(cur ^ 1);   // other buffer; cur-readers unaffected
    }
    __syncthreads();
  }
  float4 b0 = make_float4(0.f, 0.f, 0.f, 0.f), b1 = b0;
  if (bias) {
    b0 = *(const float4*)&bias[4 * tcg];
    b1 = *(const float4*)&bias[4 * tcg + 64];
  }
#pragma unroll
  for (int i = 0; i < 8; i++) {
    float4 o0 = acc0[i], o1 = acc1[i];
    o0.x += b0.x; o0.y += b0.y; o0.z += b0.z; o0.w += b0.w;
    o1.x += b1.x; o1.y += b1.y; o1.z += b1.z; o1.w += b1.w;
    *(float4*)&out[(row0 + r0 + i) * DD + 4 * tcg] = o0;
    *(float4*)&out[(row0 + r0 + i) * DD + 4 * tcg + 64] = o1;
  }
}

// ---------------- fused GAT edge kernel (unchanged, 47us) ----------------
__device__ inline float lk1(float v) { return v > 0.f ? v : NEG_SLOPE * v; }

__global__ __launch_bounds__(256, 4) void gat_edge_kernel(const float* __restrict__ P,
                                                          const float* __restrict__ Q,
                                                          const float* __restrict__ H,
                                                          const int* __restrict__ rowptr,
                                                          const int* __restrict__ col,
                                                          float* __restrict__ out) {
  int wv = threadIdx.x >> 6;
  int lane = threadIdx.x & 63;
  int dst = (blockIdx.x << 2) + wv;
  int rs = __builtin_amdgcn_readfirstlane(rowptr[dst]);
  int re = __builtin_amdgcn_readfirstlane(rowptr[dst + 1]);
  int deg = re - rs;
  int total = deg + 1;
  float2 pd = ((const float2*)(P + (size_t)dst * DD))[lane];

  float mx = -INFINITY, my = -INFINITY;
  float sx = 0.f, sy = 0.f;
  float cx = 0.f, cy = 0.f;

  for (int base = 0; base < total; base += 64) {
    int cnt = min(64, total - base);
    int e = base + lane;
    int myidx = (e < deg) ? col[rs + e] : dst;
    int i = 0;
    for (; i + 4 <= cnt; i += 4) {
      int iu = __builtin_amdgcn_readfirstlane(i);
      int n0 = __builtin_amdgcn_readlane(myidx, iu);
      int n1 = __builtin_amdgcn_readlane(myidx, iu + 1);
      int n2 = __builtin_amdgcn_readlane(myidx, iu + 2);
      int n3 = __builtin_amdgcn_readlane(myidx, iu + 3);
      float2 q0 = ((const float2*)(Q + (size_t)n0 * DD))[lane];
      float2 q1 = ((const float2*)(Q + (size_t)n1 * DD))[lane];
      float2 q2 = ((const float2*)(Q + (size_t)n2 * DD))[lane];
      float2 q3 = ((const float2*)(Q + (size_t)n3 * DD))[lane];
      float2 h0 = ((const float2*)(H + (size_t)n0 * DD))[lane];
      float2 h1 = ((const float2*)(H + (size_t)n1 * DD))[lane];
      float2 h2 = ((const float2*)(H + (size_t)n2 * DD))[lane];
      float2 h3 = ((const float2*)(H + (size_t)n3 * DD))[lane];
      float a0x = lk1(pd.x + q0.x), a0y = lk1(pd.y + q0.y);
      float a1x = lk1(pd.x + q1.x), a1y = lk1(pd.y + q1.y);
      float a2x = lk1(pd.x + q2.x), a2y = lk1(pd.y + q2.y);
      float a3x = lk1(pd.x + q3.x), a3y = lk1(pd.y + q3.y);
      float nmx = fmaxf(fmaxf(mx, fmaxf(a0x, a1x)), fmaxf(a2x, a3x));
      float nmy = fmaxf(fmaxf(my, fmaxf(a0y, a1y)), fmaxf(a2y, a3y));
      float scx = expf(mx - nmx), scy = expf(my - nmy);
      float e0x = expf(a0x - nmx), e1x = expf(a1x - nmx);
      float e2x = expf(a2x - nmx), e3x = expf(a3x - nmx);
      float e0y = expf(a0y - nmy), e1y = expf(a1y - nmy);
      float e2y = expf(a2y - nmy), e3y = expf(a3y - nmy);
      sx = sx * scx + ((e0x + e1x) + (e2x + e3x));
      sy = sy * scy + ((e0y + e1y) + (e2y + e3y));
      cx = cx * scx + ((e0x * h0.x + e1x * h1.x) + (e2x * h2.x + e3x * h3.x));
      cy = cy * scy + ((e0y * h0.y + e1y * h1.y) + (e2y * h2.y + e3y * h3.y));
      mx = nmx; my = nmy;
    }
    for (; i < cnt; i++) {
      int iu = __builtin_amdgcn_readfirstlane(i);
      int n0 = __builtin_amdgcn_readlane(myidx, iu);
      float2 q0 = ((const float2*)(Q + (size_t)n0 * DD))[lane];
      float2 h0 = ((const float2*)(H + (size_t)n0 * DD))[lane];
      float a0x = lk1(pd.x + q0.x), a0y = lk1(pd.y + q0.y);
      float nmx = fmaxf(mx, a0x), nmy = fmaxf(my, a0y);
      float scx = expf(mx - nmx), scy = expf(my - nmy);
      float e0x = expf(a0x - nmx), e0y = expf(a0y - nmy);
      sx = sx * scx + e0x;
      sy = sy * scy + e0y;
      cx = cx * scx + e0x * h0.x;
      cy = cy * scy + e0y * h0.y;
      mx = nmx; my = nmy;
    }
  }
  float2 o = make_float2(cx / (sx + 1e-16f), cy / (sy + 1e-16f));
  ((float2*)(out + (size_t)dst * DD))[lane] = o;
}

// ---------------- final stage ----------------
__global__ __launch_bounds__(256) void logits_kernel(const float* __restrict__ X,
                                                     const float* __restrict__ Wp,
                                                     const float* __restrict__ bp,
                                                     float* __restrict__ logits) {
  int w = threadIdx.x >> 6, lane = threadIdx.x & 63;
  int n = blockIdx.x * 4 + w;
  const float* xr = X + (size_t)n * DD;
  float p = xr[lane] * Wp[lane] + xr[lane + 64] * Wp[lane + 64];
  for (int off = 32; off > 0; off >>= 1) p += __shfl_down(p, off);
  if (lane == 0) logits[n] = p + bp[0];
}

__global__ __launch_bounds__(1024) void hmean_kernel(const float* __restrict__ X,
                                                     float* __restrict__ out) {
  int b = blockIdx.x;
  int t = threadIdx.x;
  int c = t & 127, part = t >> 7;
  float acc = 0.f;
  for (int i = part; i < NPG; i += 8)
    acc += X[((size_t)b * NPG + i) * DD + c];
  __shared__ float red[1024];
  red[t] = acc; __syncthreads();
  if (part == 0) {
    float s = 0.f;
#pragma unroll
    for (int p = 0; p < 8; p++) s += red[p * 128 + c];
    out[b * DD + c] = s * (1.0f / (float)NPG);
  }
}

__global__ __launch_bounds__(256) void sample1_kernel(const float* __restrict__ logits,
                                                      uint32_t ka, uint32_t kb,
                                                      int* __restrict__ idx1_ws,
                                                      float* __restrict__ p1_ws,
                                                      float* __restrict__ out) {
  int b = blockIdx.x, t = threadIdx.x;
  __shared__ float sV[256]; __shared__ int sJ[256]; __shared__ float sM[256];
  float bestV = -INFINITY; int bestJ = 1 << 30; float maxL = -INFINITY;
  for (int j = 1 + t; j < NPG; j += 256) {
    float l = logits[(size_t)b * NPG + j];
    maxL = fmaxf(maxL, l);
    float v = l + gumbel_at(ka, kb, (uint32_t)(b * 1023 + j - 1));
    if (v > bestV) { bestV = v; bestJ = j; }
  }
  sV[t] = bestV; sJ[t] = bestJ; sM[t] = maxL; __syncthreads();
  for (int off = 128; off > 0; off >>= 1) {
    if (t < off) {
      if (sV[t + off] > sV[t] || (sV[t + off] == sV[t] && sJ[t + off] < sJ[t])) {
        sV[t] = sV[t + off]; sJ[t] = sJ[t + off];
      }
      sM[t] = fmaxf(sM[t], sM[t + off]);
    }
    __syncthreads();
  }
  float M = sM[0]; int idx = sJ[0];
  __syncthreads();
  float ps = 0.f;
  for (int j = 1 + t; j < NPG; j += 256)
    ps += expf(logits[(size_t)b * NPG + j] - M);
  sV[t] = ps; __syncthreads();
  for (int off = 128; off > 0; off >>= 1) {
    if (t < off) sV[t] += sV[t + off];
    __syncthreads();
  }
  if (t == 0) {
    float S = sV[0];
    float p1 = expf(logits[(size_t)b * NPG + idx] - M) / S;
    idx1_ws[b] = idx;
    p1_ws[b] = p1;
    out[NB * DD + b] = (float)idx;  // index1
  }
}

__global__ __launch_bounds__(128) void zk_kernel(const float* __restrict__ X,
                                                 const float* __restrict__ Wa1,
                                                 const int* __restrict__ idx1,
                                                 float* __restrict__ Z) {
  int b = blockIdx.x, c = threadIdx.x;
  __shared__ float xs[128];
  int node = b * NPG + idx1[b];
  xs[c] = X[(size_t)node * DD + c];
  __syncthreads();
  float acc = 0.f;
#pragma unroll 8
  for (int k = 0; k < 128; k++) acc += xs[k] * Wa1[k * 128 + c];
  Z[b * DD + c] = acc;
}

__global__ __launch_bounds__(256) void u_kernel(const float* __restrict__ Y,
                                                const float* __restrict__ Z,
                                                const float* __restrict__ vt,
                                                const int* __restrict__ idx1,
                                                float* __restrict__ u) {
  int w = threadIdx.x >> 6, lane = threadIdx.x & 63;
  int n = blockIdx.x * 4 + w;
  int b = n >> 10;
  float t0 = tanhf(Z[b * DD + lane] + Y[(size_t)n * DD + lane]) * vt[lane];
  float t1 = tanhf(Z[b * DD + lane + 64] + Y[(size_t)n * DD + lane + 64]) * vt[lane + 64];
  float p = t0 + t1;
  for (int off = 32; off > 0; off >>= 1) p += __shfl_down(p, off);
  if (lane == 0) u[n] = ((n & (NPG - 1)) == idx1[b]) ? -INFINITY : p;
}

__global__ __launch_bounds__(256) void sample2_kernel(const float* __restrict__ u,
                                                      uint32_t ka, uint32_t kb,
                                                      const float* __restrict__ p1_ws,
                                                      float* __restrict__ out) {
  int b = blockIdx.x, t = threadIdx.x;
  __shared__ float sV[256]; __shared__ int sJ[256]; __shared__ float sM[256];
  float bestV = -INFINITY; int bestJ = 1 << 30; float maxL = -INFINITY;
  for (int j = 1 + t; j < NPG; j += 256) {
    float l = u[(size_t)b * NPG + j];
    maxL = fmaxf(maxL, l);
    float v = l + gumbel_at(ka, kb, (uint32_t)(b * 1023 + j - 1));
    if (v > bestV) { bestV = v; bestJ = j; }
  }
  sV[t] = bestV; sJ[t] = bestJ; sM[t] = maxL; __syncthreads();
  for (int off = 128; off > 0; off >>= 1) {
    if (t < off) {
      if (sV[t + off] > sV[t] || (sV[t + off] == sV[t] && sJ[t + off] < sJ[t])) {
        sV[t] = sV[t + off]; sJ[t] = sJ[t + off];
      }
      sM[t] = fmaxf(sM[t], sM[t + off]);
    }
    __syncthreads();
  }
  float M = sM[0]; int idx = sJ[0];
  __syncthreads();
  float ps = 0.f;
  for (int j = 1 + t; j < NPG; j += 256) {
    float l = u[(size_t)b * NPG + j];
    ps += expf(l - M);
  }
  sV[t] = ps; __syncthreads();
  for (int off = 128; off > 0; off >>= 1) {
    if (t < off) sV[t] += sV[t + off];
    __syncthreads();
  }
  if (t == 0) {
    float S = sV[0];
    float p2 = expf(u[(size_t)b * NPG + idx] - M) / S;
    out[NB * DD + NB + b] = (float)idx;                 // index2
    out[NB * DD + 2 * NB + b] = logf(p1_ws[b] + p2);    // log_probs
  }
}

// ---------------- host launcher ----------------
extern "C" void kernel_launch(void* const* d_in, const int* in_sizes, int n_in,
                              void* d_out, int out_size, void* d_ws, size_t ws_size,
                              hipStream_t stream) {
  const float* x  = (const float*)d_in[0];
  const int* eN   = (const int*)d_in[1];
  const int* eR0  = (const int*)d_in[2];
  const int* eR1  = (const int*)d_in[3];
  const float* W0l = (const float*)d_in[4];  const float* b0l = (const float*)d_in[5];
  const float* W0a = (const float*)d_in[6];  const float* b0a = (const float*)d_in[7];
  const float* W1l = (const float*)d_in[8];  const float* b1l = (const float*)d_in[9];
  const float* W1a = (const float*)d_in[10]; const float* b1a = (const float*)d_in[11];
  const float* W2l = (const float*)d_in[12]; const float* b2l = (const float*)d_in[13];
  const float* W2a = (const float*)d_in[14]; const float* b2a = (const float*)d_in[15];
  const float* Wp  = (const float*)d_in[16]; const float* bp  = (const float*)d_in[17];
  const float* Wa1 = (const float*)d_in[18]; const float* Wa2 = (const float*)d_in[19];
  const float* vt  = (const float*)d_in[20];
  float* out = (float*)d_out;

  char* wsb = (char*)d_ws;
  size_t off = 0;
  auto take = [&](size_t bytes) -> char* {
    char* p = wsb + off;
    off += (bytes + 255) & ~(size_t)255;
    return p;
  };
  int* rowptrAll = (int*)take((size_t)3 * (NN + 1) * sizeof(int));
  int* counts3   = (int*)take((size_t)3 * NN * sizeof(int));
  int* cursorAll = (int*)take((size_t)3 * NN * sizeof(int));
  int* colAll    = (int*)take((size_t)3 * EE * sizeof(int));
  float* bufA    = (float*)take((size_t)NN * DD * 4);
  float* bufB    = (float*)take((size_t)NN * DD * 4);
  float* hb      = (float*)take((size_t)NN * DD * 4);
  float* Pb      = (float*)take((size_t)NN * DD * 4);
  float* Qb      = (float*)take((size_t)NN * DD * 4);
  float* logits  = (float*)take((size_t)NN * 4);
  float* ub      = (float*)take((size_t)NN * 4);
  float* Zb      = (float*)take((size_t)NB * DD * 4);
  int* idx1b     = (int*)take(NB * 4);
  float* p1b     = (float*)take(NB * 4);

  // keys: jax.random.key(42) = (0,42); k1,k2 = split(key)
  uint32_t k1a, k1b, k2a, k2b;
#if USE_PARTITIONABLE
  {
    uint32_t o0, o1;
    tf2x32(0u, 42u, 0u, 0u, &o0, &o1); k1a = o0; k1b = o1;
    tf2x32(0u, 42u, 0u, 1u, &o0, &o1); k2a = o0; k2b = o1;
  }
#else
  {
    uint32_t a0, b0, a1, b1;
    tf2x32(0u, 42u, 0u, 2u, &a0, &b0);
    tf2x32(0u, 42u, 1u, 3u, &a1, &b1);
    k1a = a0; k1b = a1; k2a = b0; k2b = b1;
  }
#endif

  // ---- batched CSR build for the 3 edge sets ----
  hipMemsetAsync(counts3, 0, (size_t)3 * NN * sizeof(int), stream);
  hist3_kernel<<<3 * 1024, 256, 0, stream>>>(eN, eR0, eR1, counts3);
  scan3_kernel<<<3, 1024, 0, stream>>>(counts3, rowptrAll, cursorAll);
  scatter3_kernel<<<3 * 1024, 256, 0, stream>>>(eN, eR0, eR1, cursorAll, colAll);

  // ---- 5 GAT layers; edge sets {0,2,1,2,1} ----
  struct Layer { const float* in; float* o; const float *Wl, *bl, *Wa, *ba; int set; };
  Layer Ls[5] = {
      {x,    bufA, W0l, b0l, W0a, b0a, 0},
      {bufA, bufB, W1l, b1l, W1a, b1a, 2},
      {bufB, bufA, W2l, b2l, W2a, b2a, 1},
      {bufA, bufB, W1l, b1l, W1a, b1a, 2},
      {bufB, bufA, W2l, b2l, W2a, b2a, 1},
  };
  for (int L = 0; L < 5; L++) {
    gemm8_kernel<<<NN / 128, 256, 0, stream>>>(Ls[L].in, Ls[L].Wl, Ls[L].bl, hb);
    gemm8_kernel<<<NN / 128, 256, 0, stream>>>(hb, Ls[L].Wa, Ls[L].ba, Pb);
    gemm8_kernel<<<NN / 128, 256, 0, stream>>>(hb, Ls[L].Wa + 128 * 128, nullptr, Qb);
    gat_edge_kernel<<<NN / 4, 256, 0, stream>>>(
        Pb, Qb, hb, rowptrAll + Ls[L].set * (NN + 1),
        colAll + (size_t)Ls[L].set * EE, Ls[L].o);
  }
  const float* X = bufA;  // g4

  // ---- heads ----
  gemm8_kernel<<<NN / 128, 256, 0, stream>>>(X, Wa2, nullptr, Pb);  // Y = X @ Wa2
  logits_kernel<<<NN / 4, 256, 0, stream>>>(X, Wp, bp, logits);
  hmean_kernel<<<NB, 1024, 0, stream>>>(X, out);
  sample1_kernel<<<NB, 256, 0, stream>>>(logits, k1a, k1b, idx1b, p1b, out);
  zk_kernel<<<NB, 128, 0, stream>>>(X, Wa1, idx1b, Zb);
  u_kernel<<<NN / 4, 256, 0, stream>>>(Pb, Zb, vt, idx1b, ub);
  sample2_kernel<<<NB, 256, 0, stream>>>(ub, k2a, k2b, p1b, out);
}

// Round 9
// 837.713 us; speedup vs baseline: 2.0546x; 2.0546x over previous
//
#include <hip/hip_runtime.h>
#include <stdint.h>
#include <math.h>

#define NN 32768      // total nodes
#define EE 262144     // edges per edge set (before self loops)
#define DD 128
#define NPG 1024
#define NB 32
#define NEG_SLOPE 0.2f
#define USE_PARTITIONABLE 1

// ---------------- threefry2x32 (exact JAX algorithm) ----------------
__host__ __device__ inline void tf2x32(uint32_t k0, uint32_t k1, uint32_t c0, uint32_t c1,
                                       uint32_t* o0, uint32_t* o1) {
  uint32_t ks2 = k0 ^ k1 ^ 0x1BD11BDAu;
  uint32_t x0 = c0 + k0;
  uint32_t x1 = c1 + k1;
#define TFR(r) { x0 += x1; x1 = (x1 << (r)) | (x1 >> (32 - (r))); x1 ^= x0; }
  TFR(13) TFR(15) TFR(26) TFR(6)
  x0 += k1; x1 += ks2 + 1u;
  TFR(17) TFR(29) TFR(16) TFR(24)
  x0 += ks2; x1 += k0 + 2u;
  TFR(13) TFR(15) TFR(26) TFR(6)
  x0 += k0; x1 += k1 + 3u;
  TFR(17) TFR(29) TFR(16) TFR(24)
  x0 += k1; x1 += ks2 + 4u;
  TFR(13) TFR(15) TFR(26) TFR(6)
  x0 += ks2; x1 += k0 + 5u;
#undef TFR
  *o0 = x0; *o1 = x1;
}

__device__ inline float gumbel_from_bits(uint32_t bits) {
  float fl = __uint_as_float((bits >> 9) | 0x3f800000u) - 1.0f;
  const float tiny = 1.17549435e-38f;
  float u = fmaxf(tiny, fl + tiny);
  return -logf(-logf(u));
}

__device__ inline float gumbel_at(uint32_t ka, uint32_t kb, uint32_t f) {
#if USE_PARTITIONABLE
  uint32_t o0, o1;
  tf2x32(ka, kb, 0u, f, &o0, &o1);   // counter = 64-bit flat index (hi=0, lo=f)
  return gumbel_from_bits(o0 ^ o1);  // 32-bit draw = XOR fold of both words
#else
  const uint32_t HALF = 16368u;
  uint32_t o0, o1;
  if (f < HALF) { tf2x32(ka, kb, f, f + HALF, &o0, &o1); return gumbel_from_bits(o0); }
  else          { tf2x32(ka, kb, f - HALF, f, &o0, &o1); return gumbel_from_bits(o1); }
#endif
}

// ---------------- batched CSR build ----------------
__global__ __launch_bounds__(256) void hist3_kernel(const int* __restrict__ e0,
                                                    const int* __restrict__ e1,
                                                    const int* __restrict__ e2,
                                                    int* __restrict__ counts3) {
  int s = blockIdx.x >> 10;
  int i = (blockIdx.x & 1023) * 256 + threadIdx.x;
  const int* d = (s == 0) ? e0 : (s == 1) ? e1 : e2;
  atomicAdd(&counts3[s * NN + d[i + EE]], 1);
}

__global__ __launch_bounds__(1024) void scan3_kernel(const int* __restrict__ counts3,
                                                     int* __restrict__ rowptrAll,
                                                     int* __restrict__ cursorAll) {
  __shared__ int part[1024];
  int s = blockIdx.x;
  const int* counts = counts3 + s * NN;
  int* rowptr = rowptrAll + s * (NN + 1);
  int* cursor = cursorAll + s * NN;
  int t = threadIdx.x;
  int base = t * 32;
  int local[32];
  {
    const int4* c4 = (const int4*)(counts + base);
    int sum = 0;
#pragma unroll
    for (int v = 0; v < 8; v++) {
      int4 cc = c4[v];
      local[v * 4 + 0] = sum; sum += cc.x;
      local[v * 4 + 1] = sum; sum += cc.y;
      local[v * 4 + 2] = sum; sum += cc.z;
      local[v * 4 + 3] = sum; sum += cc.w;
    }
    part[t] = sum;
  }
  __syncthreads();
  int own = part[t];
  for (int off = 1; off < 1024; off <<= 1) {
    int v = (t >= off) ? part[t - off] : 0;
    __syncthreads();
    part[t] += v;
    __syncthreads();
  }
  int excl = part[t] - own;
  {
    int4* rp4 = (int4*)(rowptr + base);
    int4* cu4 = (int4*)(cursor + base);
#pragma unroll
    for (int v = 0; v < 8; v++) {
      int4 w;
      w.x = excl + local[v * 4 + 0];
      w.y = excl + local[v * 4 + 1];
      w.z = excl + local[v * 4 + 2];
      w.w = excl + local[v * 4 + 3];
      rp4[v] = w;
      cu4[v] = w;
    }
  }
  if (t == 1023) rowptr[NN] = part[1023];
}

__global__ __launch_bounds__(256) void scatter3_kernel(const int* __restrict__ e0,
                                                       const int* __restrict__ e1,
                                                       const int* __restrict__ e2,
                                                       int* __restrict__ cursorAll,
                                                       int* __restrict__ colAll) {
  int s = blockIdx.x >> 10;
  int i = (blockIdx.x & 1023) * 256 + threadIdx.x;
  const int* e = (s == 0) ? e0 : (s == 1) ? e1 : e2;
  int src = e[i], dst = e[i + EE];
  int p = atomicAdd(&cursorAll[s * NN + dst], 1);
  colAll[(size_t)s * EE + p] = src;
}

// ---------------- gemm8_kernel: out[128-row tile][128] = in@W (+bias) ----------------
// 256 threads, 8x8 thread tile (cols 4*tcg and 4*tcg+64), double-buffered k-chunks of 16.
// Pipeline per chunk: load-next(global) -> compute(cur) -> write-next -> ONE barrier.
// NOTE: no min-waves launch_bounds arg! R8's (256,2) capped VGPR at 128 -> acc spill
// to scratch (WRITE_SIZE 247MB vs 16MB) -> 10x slowdown. Needs ~150 VGPR.
#define FMA4(ac, s, v) { ac.x += (s) * (v).x; ac.y += (s) * (v).y; \
                         ac.z += (s) * (v).z; ac.w += (s) * (v).w; }

__global__ __launch_bounds__(256) void gemm8_kernel(const float* __restrict__ in,
                                                    const float* __restrict__ W,
                                                    const float* __restrict__ bias,
                                                    float* __restrict__ out) {
  __shared__ __align__(16) float at[2][16 * 132];  // A^T chunk (pitch 132: 2-way max)
  __shared__ __align__(16) float ws[2][16 * 128];  // W chunk
  int t = threadIdx.x;
  size_t row0 = (size_t)blockIdx.x * 128;
  int tr = t >> 4, tcg = t & 15;   // 16 row-groups x 16 col-groups
  int r0 = tr * 8;
  float4 acc0[8], acc1[8];
#pragma unroll
  for (int i = 0; i < 8; i++) {
    acc0[i] = make_float4(0.f, 0.f, 0.f, 0.f);
    acc1[i] = make_float4(0.f, 0.f, 0.f, 0.f);
  }
  int srow = t >> 2;          // 0..63
  int sc4 = (t & 3) * 4;      // 0,4,8,12
  int kkA = t >> 5;           // 0..7  (W-stage row for first f4)
  int jgA = (t & 31) * 4;     // 0..124

  float4 a0, a1, w0, w1;
  auto load_chunk = [&](int k0) {
    a0 = *(const float4*)&in[(row0 + srow) * DD + k0 + sc4];
    a1 = *(const float4*)&in[(row0 + srow + 64) * DD + k0 + sc4];
    w0 = *(const float4*)&W[(size_t)(k0 + kkA) * DD + jgA];
    w1 = *(const float4*)&W[(size_t)(k0 + kkA + 8) * DD + jgA];
  };
  auto write_chunk = [&](int b) {
    float* A = at[b];
    A[(sc4 + 0) * 132 + srow] = a0.x;
    A[(sc4 + 1) * 132 + srow] = a0.y;
    A[(sc4 + 2) * 132 + srow] = a0.z;
    A[(sc4 + 3) * 132 + srow] = a0.w;
    A[(sc4 + 0) * 132 + srow + 64] = a1.x;
    A[(sc4 + 1) * 132 + srow + 64] = a1.y;
    A[(sc4 + 2) * 132 + srow + 64] = a1.z;
    A[(sc4 + 3) * 132 + srow + 64] = a1.w;
    float* Wd = ws[b];
    *(float4*)&Wd[kkA * 128 + jgA] = w0;
    *(float4*)&Wd[(kkA + 8) * 128 + jgA] = w1;
  };

  load_chunk(0);
  write_chunk(0);
  __syncthreads();
  for (int kc = 0; kc < 8; ++kc) {
    int cur = kc & 1;
    if (kc < 7) load_chunk((kc + 1) * 16);
    const float* A = at[cur];
    const float* Wd = ws[cur];
#pragma unroll
    for (int kk = 0; kk < 16; ++kk) {
      float4 av0 = *(const float4*)&A[kk * 132 + r0];
      float4 av1 = *(const float4*)&A[kk * 132 + r0 + 4];
      float4 wv0 = *(const float4*)&Wd[kk * 128 + 4 * tcg];
      float4 wv1 = *(const float4*)&Wd[kk * 128 + 4 * tcg + 64];
      FMA4(acc0[0], av0.x, wv0); FMA4(acc1[0], av0.x, wv1);
      FMA4(acc0[1], av0.y, wv0); FMA4(acc1[1], av0.y, wv1);
      FMA4(acc0[2], av0.z, wv0); FMA4(acc1[2], av0.z, wv1);
      FMA4(acc0[3], av0.w, wv0); FMA4(acc1[3], av0.w, wv1);
      FMA4(acc0[4], av1.x, wv0); FMA4(acc1[4], av1.x, wv1);
      FMA4(acc0[5], av1.y, wv0); FMA4(acc1[5], av1.y, wv1);
      FMA4(acc0[6], av1.z, wv0); FMA4(acc1[6], av1.z, wv1);
      FMA4(acc0[7], av1.w, wv0); FMA4(acc1[7], av1.w, wv1);
    }
    if (kc < 7) {
      write_chunk(cur ^ 1);   // other buffer; cur-readers unaffected
    }
    __syncthreads();
  }
  float4 b0 = make_float4(0.f, 0.f, 0.f, 0.f), b1 = b0;
  if (bias) {
    b0 = *(const float4*)&bias[4 * tcg];
    b1 = *(const float4*)&bias[4 * tcg + 64];
  }
#pragma unroll
  for (int i = 0; i < 8; i++) {
    float4 o0 = acc0[i], o1 = acc1[i];
    o0.x += b0.x; o0.y += b0.y; o0.z += b0.z; o0.w += b0.w;
    o1.x += b1.x; o1.y += b1.y; o1.z += b1.z; o1.w += b1.w;
    *(float4*)&out[(row0 + r0 + i) * DD + 4 * tcg] = o0;
    *(float4*)&out[(row0 + r0 + i) * DD + 4 * tcg + 64] = o1;
  }
}

// ---------------- fused GAT edge kernel (unchanged, 47us) ----------------
__device__ inline float lk1(float v) { return v > 0.f ? v : NEG_SLOPE * v; }

__global__ __launch_bounds__(256, 4) void gat_edge_kernel(const float* __restrict__ P,
                                                          const float* __restrict__ Q,
                                                          const float* __restrict__ H,
                                                          const int* __restrict__ rowptr,
                                                          const int* __restrict__ col,
                                                          float* __restrict__ out) {
  int wv = threadIdx.x >> 6;
  int lane = threadIdx.x & 63;
  int dst = (blockIdx.x << 2) + wv;
  int rs = __builtin_amdgcn_readfirstlane(rowptr[dst]);
  int re = __builtin_amdgcn_readfirstlane(rowptr[dst + 1]);
  int deg = re - rs;
  int total = deg + 1;
  float2 pd = ((const float2*)(P + (size_t)dst * DD))[lane];

  float mx = -INFINITY, my = -INFINITY;
  float sx = 0.f, sy = 0.f;
  float cx = 0.f, cy = 0.f;

  for (int base = 0; base < total; base += 64) {
    int cnt = min(64, total - base);
    int e = base + lane;
    int myidx = (e < deg) ? col[rs + e] : dst;
    int i = 0;
    for (; i + 4 <= cnt; i += 4) {
      int iu = __builtin_amdgcn_readfirstlane(i);
      int n0 = __builtin_amdgcn_readlane(myidx, iu);
      int n1 = __builtin_amdgcn_readlane(myidx, iu + 1);
      int n2 = __builtin_amdgcn_readlane(myidx, iu + 2);
      int n3 = __builtin_amdgcn_readlane(myidx, iu + 3);
      float2 q0 = ((const float2*)(Q + (size_t)n0 * DD))[lane];
      float2 q1 = ((const float2*)(Q + (size_t)n1 * DD))[lane];
      float2 q2 = ((const float2*)(Q + (size_t)n2 * DD))[lane];
      float2 q3 = ((const float2*)(Q + (size_t)n3 * DD))[lane];
      float2 h0 = ((const float2*)(H + (size_t)n0 * DD))[lane];
      float2 h1 = ((const float2*)(H + (size_t)n1 * DD))[lane];
      float2 h2 = ((const float2*)(H + (size_t)n2 * DD))[lane];
      float2 h3 = ((const float2*)(H + (size_t)n3 * DD))[lane];
      float a0x = lk1(pd.x + q0.x), a0y = lk1(pd.y + q0.y);
      float a1x = lk1(pd.x + q1.x), a1y = lk1(pd.y + q1.y);
      float a2x = lk1(pd.x + q2.x), a2y = lk1(pd.y + q2.y);
      float a3x = lk1(pd.x + q3.x), a3y = lk1(pd.y + q3.y);
      float nmx = fmaxf(fmaxf(mx, fmaxf(a0x, a1x)), fmaxf(a2x, a3x));
      float nmy = fmaxf(fmaxf(my, fmaxf(a0y, a1y)), fmaxf(a2y, a3y));
      float scx = expf(mx - nmx), scy = expf(my - nmy);
      float e0x = expf(a0x - nmx), e1x = expf(a1x - nmx);
      float e2x = expf(a2x - nmx), e3x = expf(a3x - nmx);
      float e0y = expf(a0y - nmy), e1y = expf(a1y - nmy);
      float e2y = expf(a2y - nmy), e3y = expf(a3y - nmy);
      sx = sx * scx + ((e0x + e1x) + (e2x + e3x));
      sy = sy * scy + ((e0y + e1y) + (e2y + e3y));
      cx = cx * scx + ((e0x * h0.x + e1x * h1.x) + (e2x * h2.x + e3x * h3.x));
      cy = cy * scy + ((e0y * h0.y + e1y * h1.y) + (e2y * h2.y + e3y * h3.y));
      mx = nmx; my = nmy;
    }
    for (; i < cnt; i++) {
      int iu = __builtin_amdgcn_readfirstlane(i);
      int n0 = __builtin_amdgcn_readlane(myidx, iu);
      float2 q0 = ((const float2*)(Q + (size_t)n0 * DD))[lane];
      float2 h0 = ((const float2*)(H + (size_t)n0 * DD))[lane];
      float a0x = lk1(pd.x + q0.x), a0y = lk1(pd.y + q0.y);
      float nmx = fmaxf(mx, a0x), nmy = fmaxf(my, a0y);
      float scx = expf(mx - nmx), scy = expf(my - nmy);
      float e0x = expf(a0x - nmx), e0y = expf(a0y - nmy);
      sx = sx * scx + e0x;
      sy = sy * scy + e0y;
      cx = cx * scx + e0x * h0.x;
      cy = cy * scy + e0y * h0.y;
      mx = nmx; my = nmy;
    }
  }
  float2 o = make_float2(cx / (sx + 1e-16f), cy / (sy + 1e-16f));
  ((float2*)(out + (size_t)dst * DD))[lane] = o;
}

// ---------------- final stage ----------------
__global__ __launch_bounds__(256) void logits_kernel(const float* __restrict__ X,
                                                     const float* __restrict__ Wp,
                                                     const float* __restrict__ bp,
                                                     float* __restrict__ logits) {
  int w = threadIdx.x >> 6, lane = threadIdx.x & 63;
  int n = blockIdx.x * 4 + w;
  const float* xr = X + (size_t)n * DD;
  float p = xr[lane] * Wp[lane] + xr[lane + 64] * Wp[lane + 64];
  for (int off = 32; off > 0; off >>= 1) p += __shfl_down(p, off);
  if (lane == 0) logits[n] = p + bp[0];
}

__global__ __launch_bounds__(1024) void hmean_kernel(const float* __restrict__ X,
                                                     float* __restrict__ out) {
  int b = blockIdx.x;
  int t = threadIdx.x;
  int c = t & 127, part = t >> 7;
  float acc = 0.f;
  for (int i = part; i < NPG; i += 8)
    acc += X[((size_t)b * NPG + i) * DD + c];
  __shared__ float red[1024];
  red[t] = acc; __syncthreads();
  if (part == 0) {
    float s = 0.f;
#pragma unroll
    for (int p = 0; p < 8; p++) s += red[p * 128 + c];
    out[b * DD + c] = s * (1.0f / (float)NPG);
  }
}

__global__ __launch_bounds__(256) void sample1_kernel(const float* __restrict__ logits,
                                                      uint32_t ka, uint32_t kb,
                                                      int* __restrict__ idx1_ws,
                                                      float* __restrict__ p1_ws,
                                                      float* __restrict__ out) {
  int b = blockIdx.x, t = threadIdx.x;
  __shared__ float sV[256]; __shared__ int sJ[256]; __shared__ float sM[256];
  float bestV = -INFINITY; int bestJ = 1 << 30; float maxL = -INFINITY;
  for (int j = 1 + t; j < NPG; j += 256) {
    float l = logits[(size_t)b * NPG + j];
    maxL = fmaxf(maxL, l);
    float v = l + gumbel_at(ka, kb, (uint32_t)(b * 1023 + j - 1));
    if (v > bestV) { bestV = v; bestJ = j; }
  }
  sV[t] = bestV; sJ[t] = bestJ; sM[t] = maxL; __syncthreads();
  for (int off = 128; off > 0; off >>= 1) {
    if (t < off) {
      if (sV[t + off] > sV[t] || (sV[t + off] == sV[t] && sJ[t + off] < sJ[t])) {
        sV[t] = sV[t + off]; sJ[t] = sJ[t + off];
      }
      sM[t] = fmaxf(sM[t], sM[t + off]);
    }
    __syncthreads();
  }
  float M = sM[0]; int idx = sJ[0];
  __syncthreads();
  float ps = 0.f;
  for (int j = 1 + t; j < NPG; j += 256)
    ps += expf(logits[(size_t)b * NPG + j] - M);
  sV[t] = ps; __syncthreads();
  for (int off = 128; off > 0; off >>= 1) {
    if (t < off) sV[t] += sV[t + off];
    __syncthreads();
  }
  if (t == 0) {
    float S = sV[0];
    float p1 = expf(logits[(size_t)b * NPG + idx] - M) / S;
    idx1_ws[b] = idx;
    p1_ws[b] = p1;
    out[NB * DD + b] = (float)idx;  // index1
  }
}

__global__ __launch_bounds__(128) void zk_kernel(const float* __restrict__ X,
                                                 const float* __restrict__ Wa1,
                                                 const int* __restrict__ idx1,
                                                 float* __restrict__ Z) {
  int b = blockIdx.x, c = threadIdx.x;
  __shared__ float xs[128];
  int node = b * NPG + idx1[b];
  xs[c] = X[(size_t)node * DD + c];
  __syncthreads();
  float acc = 0.f;
#pragma unroll 8
  for (int k = 0; k < 128; k++) acc += xs[k] * Wa1[k * 128 + c];
  Z[b * DD + c] = acc;
}

__global__ __launch_bounds__(256) void u_kernel(const float* __restrict__ Y,
                                                const float* __restrict__ Z,
                                                const float* __restrict__ vt,
                                                const int* __restrict__ idx1,
                                                float* __restrict__ u) {
  int w = threadIdx.x >> 6, lane = threadIdx.x & 63;
  int n = blockIdx.x * 4 + w;
  int b = n >> 10;
  float t0 = tanhf(Z[b * DD + lane] + Y[(size_t)n * DD + lane]) * vt[lane];
  float t1 = tanhf(Z[b * DD + lane + 64] + Y[(size_t)n * DD + lane + 64]) * vt[lane + 64];
  float p = t0 + t1;
  for (int off = 32; off > 0; off >>= 1) p += __shfl_down(p, off);
  if (lane == 0) u[n] = ((n & (NPG - 1)) == idx1[b]) ? -INFINITY : p;
}

__global__ __launch_bounds__(256) void sample2_kernel(const float* __restrict__ u,
                                                      uint32_t ka, uint32_t kb,
                                                      const float* __restrict__ p1_ws,
                                                      float* __restrict__ out) {
  int b = blockIdx.x, t = threadIdx.x;
  __shared__ float sV[256]; __shared__ int sJ[256]; __shared__ float sM[256];
  float bestV = -INFINITY; int bestJ = 1 << 30; float maxL = -INFINITY;
  for (int j = 1 + t; j < NPG; j += 256) {
    float l = u[(size_t)b * NPG + j];
    maxL = fmaxf(maxL, l);
    float v = l + gumbel_at(ka, kb, (uint32_t)(b * 1023 + j - 1));
    if (v > bestV) { bestV = v; bestJ = j; }
  }
  sV[t] = bestV; sJ[t] = bestJ; sM[t] = maxL; __syncthreads();
  for (int off = 128; off > 0; off >>= 1) {
    if (t < off) {
      if (sV[t + off] > sV[t] || (sV[t + off] == sV[t] && sJ[t + off] < sJ[t])) {
        sV[t] = sV[t + off]; sJ[t] = sJ[t + off];
      }
      sM[t] = fmaxf(sM[t], sM[t + off]);
    }
    __syncthreads();
  }
  float M = sM[0]; int idx = sJ[0];
  __syncthreads();
  float ps = 0.f;
  for (int j = 1 + t; j < NPG; j += 256) {
    float l = u[(size_t)b * NPG + j];
    ps += expf(l - M);
  }
  sV[t] = ps; __syncthreads();
  for (int off = 128; off > 0; off >>= 1) {
    if (t < off) sV[t] += sV[t + off];
    __syncthreads();
  }
  if (t == 0) {
    float S = sV[0];
    float p2 = expf(u[(size_t)b * NPG + idx] - M) / S;
    out[NB * DD + NB + b] = (float)idx;                 // index2
    out[NB * DD + 2 * NB + b] = logf(p1_ws[b] + p2);    // log_probs
  }
}

// ---------------- host launcher ----------------
extern "C" void kernel_launch(void* const* d_in, const int* in_sizes, int n_in,
                              void* d_out, int out_size, void* d_ws, size_t ws_size,
                              hipStream_t stream) {
  const float* x  = (const float*)d_in[0];
  const int* eN   = (const int*)d_in[1];
  const int* eR0  = (const int*)d_in[2];
  const int* eR1  = (const int*)d_in[3];
  const float* W0l = (const float*)d_in[4];  const float* b0l = (const float*)d_in[5];
  const float* W0a = (const float*)d_in[6];  const float* b0a = (const float*)d_in[7];
  const float* W1l = (const float*)d_in[8];  const float* b1l = (const float*)d_in[9];
  const float* W1a = (const float*)d_in[10]; const float* b1a = (const float*)d_in[11];
  const float* W2l = (const float*)d_in[12]; const float* b2l = (const float*)d_in[13];
  const float* W2a = (const float*)d_in[14]; const float* b2a = (const float*)d_in[15];
  const float* Wp  = (const float*)d_in[16]; const float* bp  = (const float*)d_in[17];
  const float* Wa1 = (const float*)d_in[18]; const float* Wa2 = (const float*)d_in[19];
  const float* vt  = (const float*)d_in[20];
  float* out = (float*)d_out;

  char* wsb = (char*)d_ws;
  size_t off = 0;
  auto take = [&](size_t bytes) -> char* {
    char* p = wsb + off;
    off += (bytes + 255) & ~(size_t)255;
    return p;
  };
  int* rowptrAll = (int*)take((size_t)3 * (NN + 1) * sizeof(int));
  int* counts3   = (int*)take((size_t)3 * NN * sizeof(int));
  int* cursorAll = (int*)take((size_t)3 * NN * sizeof(int));
  int* colAll    = (int*)take((size_t)3 * EE * sizeof(int));
  float* bufA    = (float*)take((size_t)NN * DD * 4);
  float* bufB    = (float*)take((size_t)NN * DD * 4);
  float* hb      = (float*)take((size_t)NN * DD * 4);
  float* Pb      = (float*)take((size_t)NN * DD * 4);
  float* Qb      = (float*)take((size_t)NN * DD * 4);
  float* logits  = (float*)take((size_t)NN * 4);
  float* ub      = (float*)take((size_t)NN * 4);
  float* Zb      = (float*)take((size_t)NB * DD * 4);
  int* idx1b     = (int*)take(NB * 4);
  float* p1b     = (float*)take(NB * 4);

  // keys: jax.random.key(42) = (0,42); k1,k2 = split(key)
  uint32_t k1a, k1b, k2a, k2b;
#if USE_PARTITIONABLE
  {
    uint32_t o0, o1;
    tf2x32(0u, 42u, 0u, 0u, &o0, &o1); k1a = o0; k1b = o1;
    tf2x32(0u, 42u, 0u, 1u, &o0, &o1); k2a = o0; k2b = o1;
  }
#else
  {
    uint32_t a0, b0, a1, b1;
    tf2x32(0u, 42u, 0u, 2u, &a0, &b0);
    tf2x32(0u, 42u, 1u, 3u, &a1, &b1);
    k1a = a0; k1b = a1; k2a = b0; k2b = b1;
  }
#endif

  // ---- batched CSR build for the 3 edge sets ----
  hipMemsetAsync(counts3, 0, (size_t)3 * NN * sizeof(int), stream);
  hist3_kernel<<<3 * 1024, 256, 0, stream>>>(eN, eR0, eR1, counts3);
  scan3_kernel<<<3, 1024, 0, stream>>>(counts3, rowptrAll, cursorAll);
  scatter3_kernel<<<3 * 1024, 256, 0, stream>>>(eN, eR0, eR1, cursorAll, colAll);

  // ---- 5 GAT layers; edge sets {0,2,1,2,1} ----
  struct Layer { const float* in; float* o; const float *Wl, *bl, *Wa, *ba; int set; };
  Layer Ls[5] = {
      {x,    bufA, W0l, b0l, W0a, b0a, 0},
      {bufA, bufB, W1l, b1l, W1a, b1a, 2},
      {bufB, bufA, W2l, b2l, W2a, b2a, 1},
      {bufA, bufB, W1l, b1l, W1a, b1a, 2},
      {bufB, bufA, W2l, b2l, W2a, b2a, 1},
  };
  for (int L = 0; L < 5; L++) {
    gemm8_kernel<<<NN / 128, 256, 0, stream>>>(Ls[L].in, Ls[L].Wl, Ls[L].bl, hb);
    gemm8_kernel<<<NN / 128, 256, 0, stream>>>(hb, Ls[L].Wa, Ls[L].ba, Pb);
    gemm8_kernel<<<NN / 128, 256, 0, stream>>>(hb, Ls[L].Wa + 128 * 128, nullptr, Qb);
    gat_edge_kernel<<<NN / 4, 256, 0, stream>>>(
        Pb, Qb, hb, rowptrAll + Ls[L].set * (NN + 1),
        colAll + (size_t)Ls[L].set * EE, Ls[L].o);
  }
  const float* X = bufA;  // g4

  // ---- heads ----
  gemm8_kernel<<<NN / 128, 256, 0, stream>>>(X, Wa2, nullptr, Pb);  // Y = X @ Wa2
  logits_kernel<<<NN / 4, 256, 0, stream>>>(X, Wp, bp, logits);
  hmean_kernel<<<NB, 1024, 0, stream>>>(X, out);
  sample1_kernel<<<NB, 256, 0, stream>>>(logits, k1a, k1b, idx1b, p1b, out);
  zk_kernel<<<NB, 128, 0, stream>>>(X, Wa1, idx1b, Zb);
  u_kernel<<<NN / 4, 256, 0, stream>>>(Pb, Zb, vt, idx1b, ub);
  sample2_kernel<<<NB, 256, 0, stream>>>(ub, k2a, k2b, p1b, out);
}

// Round 10
// 778.442 us; speedup vs baseline: 2.2110x; 1.0761x over previous
//
#include <hip/hip_runtime.h>
#include <stdint.h>
#include <math.h>

#define NN 32768      // total nodes
#define EE 262144     // edges per edge set (before self loops)
#define DD 128
#define NPG 1024
#define NB 32
#define NEG_SLOPE 0.2f
#define USE_PARTITIONABLE 1

// ---------------- threefry2x32 (exact JAX algorithm) ----------------
__host__ __device__ inline void tf2x32(uint32_t k0, uint32_t k1, uint32_t c0, uint32_t c1,
                                       uint32_t* o0, uint32_t* o1) {
  uint32_t ks2 = k0 ^ k1 ^ 0x1BD11BDAu;
  uint32_t x0 = c0 + k0;
  uint32_t x1 = c1 + k1;
#define TFR(r) { x0 += x1; x1 = (x1 << (r)) | (x1 >> (32 - (r))); x1 ^= x0; }
  TFR(13) TFR(15) TFR(26) TFR(6)
  x0 += k1; x1 += ks2 + 1u;
  TFR(17) TFR(29) TFR(16) TFR(24)
  x0 += ks2; x1 += k0 + 2u;
  TFR(13) TFR(15) TFR(26) TFR(6)
  x0 += k0; x1 += k1 + 3u;
  TFR(17) TFR(29) TFR(16) TFR(24)
  x0 += k1; x1 += ks2 + 4u;
  TFR(13) TFR(15) TFR(26) TFR(6)
  x0 += ks2; x1 += k0 + 5u;
#undef TFR
  *o0 = x0; *o1 = x1;
}

__device__ inline float gumbel_from_bits(uint32_t bits) {
  float fl = __uint_as_float((bits >> 9) | 0x3f800000u) - 1.0f;
  const float tiny = 1.17549435e-38f;
  float u = fmaxf(tiny, fl + tiny);
  return -logf(-logf(u));
}

__device__ inline float gumbel_at(uint32_t ka, uint32_t kb, uint32_t f) {
#if USE_PARTITIONABLE
  uint32_t o0, o1;
  tf2x32(ka, kb, 0u, f, &o0, &o1);   // counter = 64-bit flat index (hi=0, lo=f)
  return gumbel_from_bits(o0 ^ o1);  // 32-bit draw = XOR fold of both words
#else
  const uint32_t HALF = 16368u;
  uint32_t o0, o1;
  if (f < HALF) { tf2x32(ka, kb, f, f + HALF, &o0, &o1); return gumbel_from_bits(o0); }
  else          { tf2x32(ka, kb, f - HALF, f, &o0, &o1); return gumbel_from_bits(o1); }
#endif
}

// ---------------- batched CSR build ----------------
__global__ __launch_bounds__(256) void hist3_kernel(const int* __restrict__ e0,
                                                    const int* __restrict__ e1,
                                                    const int* __restrict__ e2,
                                                    int* __restrict__ counts3) {
  int s = blockIdx.x >> 10;
  int i = (blockIdx.x & 1023) * 256 + threadIdx.x;
  const int* d = (s == 0) ? e0 : (s == 1) ? e1 : e2;
  atomicAdd(&counts3[s * NN + d[i + EE]], 1);
}

__global__ __launch_bounds__(1024) void scan3_kernel(const int* __restrict__ counts3,
                                                     int* __restrict__ rowptrAll,
                                                     int* __restrict__ cursorAll) {
  __shared__ int part[1024];
  int s = blockIdx.x;
  const int* counts = counts3 + s * NN;
  int* rowptr = rowptrAll + s * (NN + 1);
  int* cursor = cursorAll + s * NN;
  int t = threadIdx.x;
  int base = t * 32;
  int local[32];
  {
    const int4* c4 = (const int4*)(counts + base);
    int sum = 0;
#pragma unroll
    for (int v = 0; v < 8; v++) {
      int4 cc = c4[v];
      local[v * 4 + 0] = sum; sum += cc.x;
      local[v * 4 + 1] = sum; sum += cc.y;
      local[v * 4 + 2] = sum; sum += cc.z;
      local[v * 4 + 3] = sum; sum += cc.w;
    }
    part[t] = sum;
  }
  __syncthreads();
  int own = part[t];
  for (int off = 1; off < 1024; off <<= 1) {
    int v = (t >= off) ? part[t - off] : 0;
    __syncthreads();
    part[t] += v;
    __syncthreads();
  }
  int excl = part[t] - own;
  {
    int4* rp4 = (int4*)(rowptr + base);
    int4* cu4 = (int4*)(cursor + base);
#pragma unroll
    for (int v = 0; v < 8; v++) {
      int4 w;
      w.x = excl + local[v * 4 + 0];
      w.y = excl + local[v * 4 + 1];
      w.z = excl + local[v * 4 + 2];
      w.w = excl + local[v * 4 + 3];
      rp4[v] = w;
      cu4[v] = w;
    }
  }
  if (t == 1023) rowptr[NN] = part[1023];
}

__global__ __launch_bounds__(256) void scatter3_kernel(const int* __restrict__ e0,
                                                       const int* __restrict__ e1,
                                                       const int* __restrict__ e2,
                                                       int* __restrict__ cursorAll,
                                                       int* __restrict__ colAll) {
  int s = blockIdx.x >> 10;
  int i = (blockIdx.x & 1023) * 256 + threadIdx.x;
  const int* e = (s == 0) ? e0 : (s == 1) ? e1 : e2;
  int src = e[i], dst = e[i + EE];
  int p = atomicAdd(&cursorAll[s * NN + dst], 1);
  colAll[(size_t)s * EE + p] = src;
}

#define FMA4(ac, s, v) { ac.x += (s) * (v).x; ac.y += (s) * (v).y; \
                         ac.z += (s) * (v).z; ac.w += (s) * (v).w; }

// ---------------- precompute: Wbig[s] = [Wl | Wl@Wa_top | Wl@Wa_bot]  (128x384) ----------
// grid = 3 types x 16 row-blocks (8 rows each), 256 threads.
__global__ __launch_bounds__(256) void wbig_kernel(const float* __restrict__ W0l,
                                                   const float* __restrict__ W0a,
                                                   const float* __restrict__ W1l,
                                                   const float* __restrict__ W1a,
                                                   const float* __restrict__ W2l,
                                                   const float* __restrict__ W2a,
                                                   float* __restrict__ WbigAll) {
  int s = blockIdx.x >> 4, rb = blockIdx.x & 15;
  const float* Wl = (s == 0) ? W0l : (s == 1) ? W1l : W2l;
  const float* Wa = (s == 0) ? W0a : (s == 1) ? W1a : W2a;
  float* Wbig = WbigAll + (size_t)s * 128 * 384;
  __shared__ float wl[8][128];
  __shared__ float wa[16][256];
  int t = threadIdx.x;
  {
    int r = t >> 5, c4 = (t & 31) * 4;
    float4 v = *(const float4*)&Wl[(size_t)(rb * 8 + r) * 128 + c4];
    *(float4*)&wl[r][c4] = v;
    *(float4*)&Wbig[(size_t)(rb * 8 + r) * 384 + c4] = v;  // copy Wl into cols 0:128
  }
  __syncthreads();
  int r = t >> 5, cg = t & 31;
  float4 accT = make_float4(0.f, 0.f, 0.f, 0.f);
  float4 accB = make_float4(0.f, 0.f, 0.f, 0.f);
  for (int kc = 0; kc < 8; ++kc) {
    int k0 = kc * 16;
#pragma unroll
    for (int i = 0; i < 4; ++i) {
      int g = t + 256 * i;
      int kk = g >> 6, c4g = g & 63;
      const float* src = (c4g < 32)
          ? &Wa[(size_t)(k0 + kk) * 128 + c4g * 4]
          : &Wa[(size_t)(128 + k0 + kk) * 128 + (c4g - 32) * 4];
      *(float4*)&wa[kk][c4g * 4] = *(const float4*)src;
    }
    __syncthreads();
#pragma unroll
    for (int kk = 0; kk < 16; ++kk) {
      float a = wl[r][k0 + kk];
      float4 wt = *(const float4*)&wa[kk][4 * cg];
      float4 wb = *(const float4*)&wa[kk][128 + 4 * cg];
      FMA4(accT, a, wt);
      FMA4(accB, a, wb);
    }
    __syncthreads();
  }
  *(float4*)&Wbig[(size_t)(rb * 8 + r) * 384 + 128 + 4 * cg] = accT;
  *(float4*)&Wbig[(size_t)(rb * 8 + r) * 384 + 256 + 4 * cg] = accB;
}

// bbig[s] = [bl | bl@Wa_top + ba | bl@Wa_bot]  (384); grid=3, 128 threads
__global__ __launch_bounds__(128) void bbig_kernel(const float* __restrict__ b0l,
                                                   const float* __restrict__ b0a,
                                                   const float* __restrict__ W0a,
                                                   const float* __restrict__ b1l,
                                                   const float* __restrict__ b1a,
                                                   const float* __restrict__ W1a,
                                                   const float* __restrict__ b2l,
                                                   const float* __restrict__ b2a,
                                                   const float* __restrict__ W2a,
                                                   float* __restrict__ bbigAll) {
  int s = blockIdx.x, c = threadIdx.x;
  const float* bl = (s == 0) ? b0l : (s == 1) ? b1l : b2l;
  const float* ba = (s == 0) ? b0a : (s == 1) ? b1a : b2a;
  const float* Wa = (s == 0) ? W0a : (s == 1) ? W1a : W2a;
  __shared__ float blS[128];
  blS[c] = bl[c];
  __syncthreads();
  float aT = 0.f, aB = 0.f;
  for (int k = 0; k < 128; ++k) {
    aT += blS[k] * Wa[(size_t)k * 128 + c];
    aB += blS[k] * Wa[(size_t)(128 + k) * 128 + c];
  }
  float* bb = bbigAll + s * 384;
  bb[c] = blS[c];
  bb[128 + c] = aT + ba[c];
  bb[256 + c] = aB;
}

// ---------------- fused384: (h|P|Q)[64-row tile] = in @ Wbig (+bbig) ----------------
// 256 threads, M=64, N=384; thread tile 8 rows x 12 cols (4cg + {0,128,256});
// double-buffered k-chunks of 16; grid 512 = 2 blocks/CU.
// NOTE: no min-waves launch_bounds arg (R8 lesson: (256,2) caps VGPR at 128 -> spill).
__global__ __launch_bounds__(256) void fused384_kernel(const float* __restrict__ in,
                                                       const float* __restrict__ Wbig,
                                                       const float* __restrict__ bbig,
                                                       float* __restrict__ h,
                                                       float* __restrict__ P,
                                                       float* __restrict__ Q) {
  __shared__ __align__(16) float at[2][16 * 68];    // A^T chunk (pitch 68: 2-way max)
  __shared__ __align__(16) float wsb[2][16 * 384];  // Wbig chunk
  int t = threadIdx.x;
  size_t row0 = (size_t)blockIdx.x * 64;
  int rowg = t >> 5, cg = t & 31;
  int r0 = rowg * 8;
  float4 acc0[8], acc1[8], acc2[8];
#pragma unroll
  for (int i = 0; i < 8; i++) {
    acc0[i] = make_float4(0.f, 0.f, 0.f, 0.f);
    acc1[i] = make_float4(0.f, 0.f, 0.f, 0.f);
    acc2[i] = make_float4(0.f, 0.f, 0.f, 0.f);
  }
  int srow = t >> 2, sc4 = (t & 3) * 4;
  int wkk[6], wc4[6];
#pragma unroll
  for (int i = 0; i < 6; i++) {
    int g = t + 256 * i;
    wkk[i] = g / 96;
    wc4[i] = (g % 96) * 4;
  }
  float4 aR;
  float4 wR[6];
  auto load_chunk = [&](int k0) {
    aR = *(const float4*)&in[(row0 + srow) * DD + k0 + sc4];
#pragma unroll
    for (int i = 0; i < 6; i++)
      wR[i] = *(const float4*)&Wbig[(size_t)(k0 + wkk[i]) * 384 + wc4[i]];
  };
  auto write_chunk = [&](int b) {
    float* A = at[b];
    A[(sc4 + 0) * 68 + srow] = aR.x;
    A[(sc4 + 1) * 68 + srow] = aR.y;
    A[(sc4 + 2) * 68 + srow] = aR.z;
    A[(sc4 + 3) * 68 + srow] = aR.w;
    float* Wd = wsb[b];
#pragma unroll
    for (int i = 0; i < 6; i++)
      *(float4*)&Wd[wkk[i] * 384 + wc4[i]] = wR[i];
  };

  load_chunk(0);
  write_chunk(0);
  __syncthreads();
  for (int kc = 0; kc < 8; ++kc) {
    int cur = kc & 1;
    if (kc < 7) load_chunk((kc + 1) * 16);
    const float* A = at[cur];
    const float* Wd = wsb[cur];
#pragma unroll 4
    for (int kk = 0; kk < 16; ++kk) {
      float4 av0 = *(const float4*)&A[kk * 68 + r0];
      float4 av1 = *(const float4*)&A[kk * 68 + r0 + 4];
      float4 wv0 = *(const float4*)&Wd[kk * 384 + 4 * cg];
      float4 wv1 = *(const float4*)&Wd[kk * 384 + 4 * cg + 128];
      float4 wv2 = *(const float4*)&Wd[kk * 384 + 4 * cg + 256];
      FMA4(acc0[0], av0.x, wv0); FMA4(acc1[0], av0.x, wv1); FMA4(acc2[0], av0.x, wv2);
      FMA4(acc0[1], av0.y, wv0); FMA4(acc1[1], av0.y, wv1); FMA4(acc2[1], av0.y, wv2);
      FMA4(acc0[2], av0.z, wv0); FMA4(acc1[2], av0.z, wv1); FMA4(acc2[2], av0.z, wv2);
      FMA4(acc0[3], av0.w, wv0); FMA4(acc1[3], av0.w, wv1); FMA4(acc2[3], av0.w, wv2);
      FMA4(acc0[4], av1.x, wv0); FMA4(acc1[4], av1.x, wv1); FMA4(acc2[4], av1.x, wv2);
      FMA4(acc0[5], av1.y, wv0); FMA4(acc1[5], av1.y, wv1); FMA4(acc2[5], av1.y, wv2);
      FMA4(acc0[6], av1.z, wv0); FMA4(acc1[6], av1.z, wv1); FMA4(acc2[6], av1.z, wv2);
      FMA4(acc0[7], av1.w, wv0); FMA4(acc1[7], av1.w, wv1); FMA4(acc2[7], av1.w, wv2);
    }
    if (kc < 7) write_chunk(cur ^ 1);
    __syncthreads();
  }
  float4 b0 = *(const float4*)&bbig[4 * cg];
  float4 b1 = *(const float4*)&bbig[128 + 4 * cg];
  float4 b2 = *(const float4*)&bbig[256 + 4 * cg];
#pragma unroll
  for (int i = 0; i < 8; i++) {
    size_t orow = (row0 + r0 + i) * DD + 4 * cg;
    float4 o0 = acc0[i], o1 = acc1[i], o2 = acc2[i];
    o0.x += b0.x; o0.y += b0.y; o0.z += b0.z; o0.w += b0.w;
    o1.x += b1.x; o1.y += b1.y; o1.z += b1.z; o1.w += b1.w;
    o2.x += b2.x; o2.y += b2.y; o2.z += b2.z; o2.w += b2.w;
    *(float4*)&h[orow] = o0;
    *(float4*)&P[orow] = o1;
    *(float4*)&Q[orow] = o2;
  }
}

// ---------------- gemm8_kernel (kept for head Y = X@Wa2; ~30us) ----------------
__global__ __launch_bounds__(256) void gemm8_kernel(const float* __restrict__ in,
                                                    const float* __restrict__ W,
                                                    const float* __restrict__ bias,
                                                    float* __restrict__ out) {
  __shared__ __align__(16) float at[2][16 * 132];
  __shared__ __align__(16) float ws[2][16 * 128];
  int t = threadIdx.x;
  size_t row0 = (size_t)blockIdx.x * 128;
  int tr = t >> 4, tcg = t & 15;
  int r0 = tr * 8;
  float4 acc0[8], acc1[8];
#pragma unroll
  for (int i = 0; i < 8; i++) {
    acc0[i] = make_float4(0.f, 0.f, 0.f, 0.f);
    acc1[i] = make_float4(0.f, 0.f, 0.f, 0.f);
  }
  int srow = t >> 2;
  int sc4 = (t & 3) * 4;
  int kkA = t >> 5;
  int jgA = (t & 31) * 4;

  float4 a0, a1, w0, w1;
  auto load_chunk = [&](int k0) {
    a0 = *(const float4*)&in[(row0 + srow) * DD + k0 + sc4];
    a1 = *(const float4*)&in[(row0 + srow + 64) * DD + k0 + sc4];
    w0 = *(const float4*)&W[(size_t)(k0 + kkA) * DD + jgA];
    w1 = *(const float4*)&W[(size_t)(k0 + kkA + 8) * DD + jgA];
  };
  auto write_chunk = [&](int b) {
    float* A = at[b];
    A[(sc4 + 0) * 132 + srow] = a0.x;
    A[(sc4 + 1) * 132 + srow] = a0.y;
    A[(sc4 + 2) * 132 + srow] = a0.z;
    A[(sc4 + 3) * 132 + srow] = a0.w;
    A[(sc4 + 0) * 132 + srow + 64] = a1.x;
    A[(sc4 + 1) * 132 + srow + 64] = a1.y;
    A[(sc4 + 2) * 132 + srow + 64] = a1.z;
    A[(sc4 + 3) * 132 + srow + 64] = a1.w;
    float* Wd = ws[b];
    *(float4*)&Wd[kkA * 128 + jgA] = w0;
    *(float4*)&Wd[(kkA + 8) * 128 + jgA] = w1;
  };

  load_chunk(0);
  write_chunk(0);
  __syncthreads();
  for (int kc = 0; kc < 8; ++kc) {
    int cur = kc & 1;
    if (kc < 7) load_chunk((kc + 1) * 16);
    const float* A = at[cur];
    const float* Wd = ws[cur];
#pragma unroll
    for (int kk = 0; kk < 16; ++kk) {
      float4 av0 = *(const float4*)&A[kk * 132 + r0];
      float4 av1 = *(const float4*)&A[kk * 132 + r0 + 4];
      float4 wv0 = *(const float4*)&Wd[kk * 128 + 4 * tcg];
      float4 wv1 = *(const float4*)&Wd[kk * 128 + 4 * tcg + 64];
      FMA4(acc0[0], av0.x, wv0); FMA4(acc1[0], av0.x, wv1);
      FMA4(acc0[1], av0.y, wv0); FMA4(acc1[1], av0.y, wv1);
      FMA4(acc0[2], av0.z, wv0); FMA4(acc1[2], av0.z, wv1);
      FMA4(acc0[3], av0.w, wv0); FMA4(acc1[3], av0.w, wv1);
      FMA4(acc0[4], av1.x, wv0); FMA4(acc1[4], av1.x, wv1);
      FMA4(acc0[5], av1.y, wv0); FMA4(acc1[5], av1.y, wv1);
      FMA4(acc0[6], av1.z, wv0); FMA4(acc1[6], av1.z, wv1);
      FMA4(acc0[7], av1.w, wv0); FMA4(acc1[7], av1.w, wv1);
    }
    if (kc < 7) write_chunk(cur ^ 1);
    __syncthreads();
  }
  float4 b0 = make_float4(0.f, 0.f, 0.f, 0.f), b1 = b0;
  if (bias) {
    b0 = *(const float4*)&bias[4 * tcg];
    b1 = *(const float4*)&bias[4 * tcg + 64];
  }
#pragma unroll
  for (int i = 0; i < 8; i++) {
    float4 o0 = acc0[i], o1 = acc1[i];
    o0.x += b0.x; o0.y += b0.y; o0.z += b0.z; o0.w += b0.w;
    o1.x += b1.x; o1.y += b1.y; o1.z += b1.z; o1.w += b1.w;
    *(float4*)&out[(row0 + r0 + i) * DD + 4 * tcg] = o0;
    *(float4*)&out[(row0 + r0 + i) * DD + 4 * tcg + 64] = o1;
  }
}

// ---------------- fused GAT edge kernel (unchanged, 47us) ----------------
__device__ inline float lk1(float v) { return v > 0.f ? v : NEG_SLOPE * v; }

__global__ __launch_bounds__(256, 4) void gat_edge_kernel(const float* __restrict__ P,
                                                          const float* __restrict__ Q,
                                                          const float* __restrict__ H,
                                                          const int* __restrict__ rowptr,
                                                          const int* __restrict__ col,
                                                          float* __restrict__ out) {
  int wv = threadIdx.x >> 6;
  int lane = threadIdx.x & 63;
  int dst = (blockIdx.x << 2) + wv;
  int rs = __builtin_amdgcn_readfirstlane(rowptr[dst]);
  int re = __builtin_amdgcn_readfirstlane(rowptr[dst + 1]);
  int deg = re - rs;
  int total = deg + 1;
  float2 pd = ((const float2*)(P + (size_t)dst * DD))[lane];

  float mx = -INFINITY, my = -INFINITY;
  float sx = 0.f, sy = 0.f;
  float cx = 0.f, cy = 0.f;

  for (int base = 0; base < total; base += 64) {
    int cnt = min(64, total - base);
    int e = base + lane;
    int myidx = (e < deg) ? col[rs + e] : dst;
    int i = 0;
    for (; i + 4 <= cnt; i += 4) {
      int iu = __builtin_amdgcn_readfirstlane(i);
      int n0 = __builtin_amdgcn_readlane(myidx, iu);
      int n1 = __builtin_amdgcn_readlane(myidx, iu + 1);
      int n2 = __builtin_amdgcn_readlane(myidx, iu + 2);
      int n3 = __builtin_amdgcn_readlane(myidx, iu + 3);
      float2 q0 = ((const float2*)(Q + (size_t)n0 * DD))[lane];
      float2 q1 = ((const float2*)(Q + (size_t)n1 * DD))[lane];
      float2 q2 = ((const float2*)(Q + (size_t)n2 * DD))[lane];
      float2 q3 = ((const float2*)(Q + (size_t)n3 * DD))[lane];
      float2 h0 = ((const float2*)(H + (size_t)n0 * DD))[lane];
      float2 h1 = ((const float2*)(H + (size_t)n1 * DD))[lane];
      float2 h2 = ((const float2*)(H + (size_t)n2 * DD))[lane];
      float2 h3 = ((const float2*)(H + (size_t)n3 * DD))[lane];
      float a0x = lk1(pd.x + q0.x), a0y = lk1(pd.y + q0.y);
      float a1x = lk1(pd.x + q1.x), a1y = lk1(pd.y + q1.y);
      float a2x = lk1(pd.x + q2.x), a2y = lk1(pd.y + q2.y);
      float a3x = lk1(pd.x + q3.x), a3y = lk1(pd.y + q3.y);
      float nmx = fmaxf(fmaxf(mx, fmaxf(a0x, a1x)), fmaxf(a2x, a3x));
      float nmy = fmaxf(fmaxf(my, fmaxf(a0y, a1y)), fmaxf(a2y, a3y));
      float scx = expf(mx - nmx), scy = expf(my - nmy);
      float e0x = expf(a0x - nmx), e1x = expf(a1x - nmx);
      float e2x = expf(a2x - nmx), e3x = expf(a3x - nmx);
      float e0y = expf(a0y - nmy), e1y = expf(a1y - nmy);
      float e2y = expf(a2y - nmy), e3y = expf(a3y - nmy);
      sx = sx * scx + ((e0x + e1x) + (e2x + e3x));
      sy = sy * scy + ((e0y + e1y) + (e2y + e3y));
      cx = cx * scx + ((e0x * h0.x + e1x * h1.x) + (e2x * h2.x + e3x * h3.x));
      cy = cy * scy + ((e0y * h0.y + e1y * h1.y) + (e2y * h2.y + e3y * h3.y));
      mx = nmx; my = nmy;
    }
    for (; i < cnt; i++) {
      int iu = __builtin_amdgcn_readfirstlane(i);
      int n0 = __builtin_amdgcn_readlane(myidx, iu);
      float2 q0 = ((const float2*)(Q + (size_t)n0 * DD))[lane];
      float2 h0 = ((const float2*)(H + (size_t)n0 * DD))[lane];
      float a0x = lk1(pd.x + q0.x), a0y = lk1(pd.y + q0.y);
      float nmx = fmaxf(mx, a0x), nmy = fmaxf(my, a0y);
      float scx = expf(mx - nmx), scy = expf(my - nmy);
      float e0x = expf(a0x - nmx), e0y = expf(a0y - nmy);
      sx = sx * scx + e0x;
      sy = sy * scy + e0y;
      cx = cx * scx + e0x * h0.x;
      cy = cy * scy + e0y * h0.y;
      mx = nmx; my = nmy;
    }
  }
  float2 o = make_float2(cx / (sx + 1e-16f), cy / (sy + 1e-16f));
  ((float2*)(out + (size_t)dst * DD))[lane] = o;
}

// ---------------- final stage ----------------
__global__ __launch_bounds__(256) void logits_kernel(const float* __restrict__ X,
                                                     const float* __restrict__ Wp,
                                                     const float* __restrict__ bp,
                                                     float* __restrict__ logits) {
  int w = threadIdx.x >> 6, lane = threadIdx.x & 63;
  int n = blockIdx.x * 4 + w;
  const float* xr = X + (size_t)n * DD;
  float p = xr[lane] * Wp[lane] + xr[lane + 64] * Wp[lane + 64];
  for (int off = 32; off > 0; off >>= 1) p += __shfl_down(p, off);
  if (lane == 0) logits[n] = p + bp[0];
}

__global__ __launch_bounds__(1024) void hmean_kernel(const float* __restrict__ X,
                                                     float* __restrict__ out) {
  int b = blockIdx.x;
  int t = threadIdx.x;
  int c = t & 127, part = t >> 7;
  float acc = 0.f;
  for (int i = part; i < NPG; i += 8)
    acc += X[((size_t)b * NPG + i) * DD + c];
  __shared__ float red[1024];
  red[t] = acc; __syncthreads();
  if (part == 0) {
    float s = 0.f;
#pragma unroll
    for (int p = 0; p < 8; p++) s += red[p * 128 + c];
    out[b * DD + c] = s * (1.0f / (float)NPG);
  }
}

__global__ __launch_bounds__(256) void sample1_kernel(const float* __restrict__ logits,
                                                      uint32_t ka, uint32_t kb,
                                                      int* __restrict__ idx1_ws,
                                                      float* __restrict__ p1_ws,
                                                      float* __restrict__ out) {
  int b = blockIdx.x, t = threadIdx.x;
  __shared__ float sV[256]; __shared__ int sJ[256]; __shared__ float sM[256];
  float bestV = -INFINITY; int bestJ = 1 << 30; float maxL = -INFINITY;
  for (int j = 1 + t; j < NPG; j += 256) {
    float l = logits[(size_t)b * NPG + j];
    maxL = fmaxf(maxL, l);
    float v = l + gumbel_at(ka, kb, (uint32_t)(b * 1023 + j - 1));
    if (v > bestV) { bestV = v; bestJ = j; }
  }
  sV[t] = bestV; sJ[t] = bestJ; sM[t] = maxL; __syncthreads();
  for (int off = 128; off > 0; off >>= 1) {
    if (t < off) {
      if (sV[t + off] > sV[t] || (sV[t + off] == sV[t] && sJ[t + off] < sJ[t])) {
        sV[t] = sV[t + off]; sJ[t] = sJ[t + off];
      }
      sM[t] = fmaxf(sM[t], sM[t + off]);
    }
    __syncthreads();
  }
  float M = sM[0]; int idx = sJ[0];
  __syncthreads();
  float ps = 0.f;
  for (int j = 1 + t; j < NPG; j += 256)
    ps += expf(logits[(size_t)b * NPG + j] - M);
  sV[t] = ps; __syncthreads();
  for (int off = 128; off > 0; off >>= 1) {
    if (t < off) sV[t] += sV[t + off];
    __syncthreads();
  }
  if (t == 0) {
    float S = sV[0];
    float p1 = expf(logits[(size_t)b * NPG + idx] - M) / S;
    idx1_ws[b] = idx;
    p1_ws[b] = p1;
    out[NB * DD + b] = (float)idx;  // index1
  }
}

__global__ __launch_bounds__(128) void zk_kernel(const float* __restrict__ X,
                                                 const float* __restrict__ Wa1,
                                                 const int* __restrict__ idx1,
                                                 float* __restrict__ Z) {
  int b = blockIdx.x, c = threadIdx.x;
  __shared__ float xs[128];
  int node = b * NPG + idx1[b];
  xs[c] = X[(size_t)node * DD + c];
  __syncthreads();
  float acc = 0.f;
#pragma unroll 8
  for (int k = 0; k < 128; k++) acc += xs[k] * Wa1[k * 128 + c];
  Z[b * DD + c] = acc;
}

__global__ __launch_bounds__(256) void u_kernel(const float* __restrict__ Y,
                                                const float* __restrict__ Z,
                                                const float* __restrict__ vt,
                                                const int* __restrict__ idx1,
                                                float* __restrict__ u) {
  int w = threadIdx.x >> 6, lane = threadIdx.x & 63;
  int n = blockIdx.x * 4 + w;
  int b = n >> 10;
  float t0 = tanhf(Z[b * DD + lane] + Y[(size_t)n * DD + lane]) * vt[lane];
  float t1 = tanhf(Z[b * DD + lane + 64] + Y[(size_t)n * DD + lane + 64]) * vt[lane + 64];
  float p = t0 + t1;
  for (int off = 32; off > 0; off >>= 1) p += __shfl_down(p, off);
  if (lane == 0) u[n] = ((n & (NPG - 1)) == idx1[b]) ? -INFINITY : p;
}

__global__ __launch_bounds__(256) void sample2_kernel(const float* __restrict__ u,
                                                      uint32_t ka, uint32_t kb,
                                                      const float* __restrict__ p1_ws,
                                                      float* __restrict__ out) {
  int b = blockIdx.x, t = threadIdx.x;
  __shared__ float sV[256]; __shared__ int sJ[256]; __shared__ float sM[256];
  float bestV = -INFINITY; int bestJ = 1 << 30; float maxL = -INFINITY;
  for (int j = 1 + t; j < NPG; j += 256) {
    float l = u[(size_t)b * NPG + j];
    maxL = fmaxf(maxL, l);
    float v = l + gumbel_at(ka, kb, (uint32_t)(b * 1023 + j - 1));
    if (v > bestV) { bestV = v; bestJ = j; }
  }
  sV[t] = bestV; sJ[t] = bestJ; sM[t] = maxL; __syncthreads();
  for (int off = 128; off > 0; off >>= 1) {
    if (t < off) {
      if (sV[t + off] > sV[t] || (sV[t + off] == sV[t] && sJ[t + off] < sJ[t])) {
        sV[t] = sV[t + off]; sJ[t] = sJ[t + off];
      }
      sM[t] = fmaxf(sM[t], sM[t + off]);
    }
    __syncthreads();
  }
  float M = sM[0]; int idx = sJ[0];
  __syncthreads();
  float ps = 0.f;
  for (int j = 1 + t; j < NPG; j += 256) {
    float l = u[(size_t)b * NPG + j];
    ps += expf(l - M);
  }
  sV[t] = ps; __syncthreads();
  for (int off = 128; off > 0; off >>= 1) {
    if (t < off) sV[t] += sV[t + off];
    __syncthreads();
  }
  if (t == 0) {
    float S = sV[0];
    float p2 = expf(u[(size_t)b * NPG + idx] - M) / S;
    out[NB * DD + NB + b] = (float)idx;                 // index2
    out[NB * DD + 2 * NB + b] = logf(p1_ws[b] + p2);    // log_probs
  }
}

// ---------------- host launcher ----------------
extern "C" void kernel_launch(void* const* d_in, const int* in_sizes, int n_in,
                              void* d_out, int out_size, void* d_ws, size_t ws_size,
                              hipStream_t stream) {
  const float* x  = (const float*)d_in[0];
  const int* eN   = (const int*)d_in[1];
  const int* eR0  = (const int*)d_in[2];
  const int* eR1  = (const int*)d_in[3];
  const float* W0l = (const float*)d_in[4];  const float* b0l = (const float*)d_in[5];
  const float* W0a = (const float*)d_in[6];  const float* b0a = (const float*)d_in[7];
  const float* W1l = (const float*)d_in[8];  const float* b1l = (const float*)d_in[9];
  const float* W1a = (const float*)d_in[10]; const float* b1a = (const float*)d_in[11];
  const float* W2l = (const float*)d_in[12]; const float* b2l = (const float*)d_in[13];
  const float* W2a = (const float*)d_in[14]; const float* b2a = (const float*)d_in[15];
  const float* Wp  = (const float*)d_in[16]; const float* bp  = (const float*)d_in[17];
  const float* Wa1 = (const float*)d_in[18]; const float* Wa2 = (const float*)d_in[19];
  const float* vt  = (const float*)d_in[20];
  float* out = (float*)d_out;

  char* wsb = (char*)d_ws;
  size_t off = 0;
  auto take = [&](size_t bytes) -> char* {
    char* p = wsb + off;
    off += (bytes + 255) & ~(size_t)255;
    return p;
  };
  int* rowptrAll = (int*)take((size_t)3 * (NN + 1) * sizeof(int));
  int* counts3   = (int*)take((size_t)3 * NN * sizeof(int));
  int* cursorAll = (int*)take((size_t)3 * NN * sizeof(int));
  int* colAll    = (int*)take((size_t)3 * EE * sizeof(int));
  float* bufA    = (float*)take((size_t)NN * DD * 4);
  float* bufB    = (float*)take((size_t)NN * DD * 4);
  float* hb      = (float*)take((size_t)NN * DD * 4);
  float* Pb      = (float*)take((size_t)NN * DD * 4);
  float* Qb      = (float*)take((size_t)NN * DD * 4);
  float* logits  = (float*)take((size_t)NN * 4);
  float* ub      = (float*)take((size_t)NN * 4);
  float* Zb      = (float*)take((size_t)NB * DD * 4);
  int* idx1b     = (int*)take(NB * 4);
  float* p1b     = (float*)take(NB * 4);
  float* WbigAll = (float*)take((size_t)3 * 128 * 384 * 4);
  float* bbigAll = (float*)take((size_t)3 * 384 * 4);

  // keys: jax.random.key(42) = (0,42); k1,k2 = split(key)
  uint32_t k1a, k1b, k2a, k2b;
#if USE_PARTITIONABLE
  {
    uint32_t o0, o1;
    tf2x32(0u, 42u, 0u, 0u, &o0, &o1); k1a = o0; k1b = o1;
    tf2x32(0u, 42u, 0u, 1u, &o0, &o1); k2a = o0; k2b = o1;
  }
#else
  {
    uint32_t a0, b0, a1, b1;
    tf2x32(0u, 42u, 0u, 2u, &a0, &b0);
    tf2x32(0u, 42u, 1u, 3u, &a1, &b1);
    k1a = a0; k1b = a1; k2a = b0; k2b = b1;
  }
#endif

  // ---- precompute composite weights + batched CSR build ----
  wbig_kernel<<<48, 256, 0, stream>>>(W0l, W0a, W1l, W1a, W2l, W2a, WbigAll);
  bbig_kernel<<<3, 128, 0, stream>>>(b0l, b0a, W0a, b1l, b1a, W1a, b2l, b2a, W2a, bbigAll);
  hipMemsetAsync(counts3, 0, (size_t)3 * NN * sizeof(int), stream);
  hist3_kernel<<<3 * 1024, 256, 0, stream>>>(eN, eR0, eR1, counts3);
  scan3_kernel<<<3, 1024, 0, stream>>>(counts3, rowptrAll, cursorAll);
  scatter3_kernel<<<3 * 1024, 256, 0, stream>>>(eN, eR0, eR1, cursorAll, colAll);

  // ---- 5 GAT layers; types {0,1,2,1,2}; edge sets {0,2,1,2,1} ----
  struct Layer { const float* in; float* o; int type; int set; };
  Layer Ls[5] = {
      {x,    bufA, 0, 0},
      {bufA, bufB, 1, 2},
      {bufB, bufA, 2, 1},
      {bufA, bufB, 1, 2},
      {bufB, bufA, 2, 1},
  };
  for (int L = 0; L < 5; L++) {
    fused384_kernel<<<NN / 64, 256, 0, stream>>>(
        Ls[L].in, WbigAll + (size_t)Ls[L].type * 128 * 384,
        bbigAll + (size_t)Ls[L].type * 384, hb, Pb, Qb);
    gat_edge_kernel<<<NN / 4, 256, 0, stream>>>(
        Pb, Qb, hb, rowptrAll + Ls[L].set * (NN + 1),
        colAll + (size_t)Ls[L].set * EE, Ls[L].o);
  }
  const float* X = bufA;  // g4

  // ---- heads ----
  gemm8_kernel<<<NN / 128, 256, 0, stream>>>(X, Wa2, nullptr, Pb);  // Y = X @ Wa2
  logits_kernel<<<NN / 4, 256, 0, stream>>>(X, Wp, bp, logits);
  hmean_kernel<<<NB, 1024, 0, stream>>>(X, out);
  sample1_kernel<<<NB, 256, 0, stream>>>(logits, k1a, k1b, idx1b, p1b, out);
  zk_kernel<<<NB, 128, 0, stream>>>(X, Wa1, idx1b, Zb);
  u_kernel<<<NN / 4, 256, 0, stream>>>(Pb, Zb, vt, idx1b, ub);
  sample2_kernel<<<NB, 256, 0, stream>>>(ub, k2a, k2b, p1b, out);
}